// Round 8
// baseline (706.042 us; speedup 1.0000x reference)
//
#include <hip/hip_runtime.h>
#include <cstddef>

#define D 128
#define CHUNK 1024
#define BM 64        // rows per layer block (4 waves; 2M x 2N wave grid in MLP)
#define LDPF 132     // f32 row stride for hacc/ys (528B, 16B-aligned)
#define LDSH 136     // short row stride for t_hi (272B)

typedef __attribute__((ext_vector_type(8))) short s16x8;
typedef __attribute__((ext_vector_type(4))) float f32x4;
typedef __attribute__((ext_vector_type(2))) float f32x2;

__device__ __forceinline__ unsigned short f2bf(float f) {
  unsigned u = __builtin_bit_cast(unsigned, f);
  u += 0x7FFFu + ((u >> 16) & 1u);
  return (unsigned short)(u >> 16);
}
__device__ __forceinline__ float bf2f(unsigned short h) {
  unsigned u = ((unsigned)h) << 16;
  return __builtin_bit_cast(float, u);
}
__device__ __forceinline__ unsigned f32x4_to_fp8(float4 v) {
  int r = __builtin_amdgcn_cvt_pk_fp8_f32(v.x, v.y, 0, false);
  r = __builtin_amdgcn_cvt_pk_fp8_f32(v.z, v.w, r, true);
  return (unsigned)r;
}

// ---------------- CSR build (once per call) ----------------
__global__ __launch_bounds__(256) void hist_kernel(const int* __restrict__ ei,
                                                   int* __restrict__ deg, int E) {
  int e = blockIdx.x * 256 + threadIdx.x;
  if (e < E) atomicAdd(&deg[ei[E + e]], 1);
}

__global__ __launch_bounds__(256) void partial_kernel(const int* __restrict__ deg,
                                                      int* __restrict__ partial, int N) {
  __shared__ int s[256];
  int base = blockIdx.x * CHUNK;
  int sum = 0;
  for (int j = threadIdx.x; j < CHUNK; j += 256) {
    int idx = base + j;
    sum += (idx < N) ? deg[idx] : 0;
  }
  s[threadIdx.x] = sum;
  __syncthreads();
  for (int ofs = 128; ofs > 0; ofs >>= 1) {
    if (threadIdx.x < ofs) s[threadIdx.x] += s[threadIdx.x + ofs];
    __syncthreads();
  }
  if (threadIdx.x == 0) partial[blockIdx.x] = s[0];
}

__global__ __launch_bounds__(1024) void scanpart_kernel(int* partial, int nb) {
  __shared__ int s[1024];
  int tid = threadIdx.x;
  int v = (tid < nb) ? partial[tid] : 0;
  s[tid] = v;
  __syncthreads();
  for (int o = 1; o < 1024; o <<= 1) {
    int t = (tid >= o) ? s[tid - o] : 0;
    __syncthreads();
    s[tid] += t;
    __syncthreads();
  }
  if (tid < nb) partial[tid] = s[tid] - v;
}

__global__ __launch_bounds__(256) void chunkscan_kernel(const int* __restrict__ deg,
                                                        const int* __restrict__ partial,
                                                        int* __restrict__ off, int N) {
  __shared__ int ws[4];
  int base = blockIdx.x * CHUNK;
  int i0 = base + threadIdx.x * 4;
  int d[4];
  int s = 0;
#pragma unroll
  for (int k = 0; k < 4; ++k) {
    d[k] = (i0 + k < N) ? deg[i0 + k] : 0;
    s += d[k];
  }
  int lane = threadIdx.x & 63;
  int incl = s;
  for (int o = 1; o < 64; o <<= 1) {
    int v = __shfl_up(incl, o, 64);
    if (lane >= o) incl += v;
  }
  int wave = threadIdx.x >> 6;
  if (lane == 63) ws[wave] = incl;
  __syncthreads();
  int wofs = 0;
  for (int w = 0; w < wave; ++w) wofs += ws[w];
  int run = partial[blockIdx.x] + wofs + (incl - s);
#pragma unroll
  for (int k = 0; k < 4; ++k) {
    int idx = i0 + k;
    if (idx < N) {
      off[idx] = run;
      run += d[k];
      if (idx == N - 1) off[N] = run;
    }
  }
}

// scatter + fp8 convert fused: half-wave per edge, ea read is sequential
__global__ __launch_bounds__(256) void scatter_conv_kernel(
    const int* __restrict__ ei, const float* __restrict__ ea,
    const int* __restrict__ off, int* __restrict__ cursor,
    int2* __restrict__ spd, unsigned char* __restrict__ eap, int E) {
  int t = blockIdx.x * 256 + threadIdx.x;
  int lane = t & 31;
  int e = t >> 5;
  if (e >= E) return;
  int p = 0;
  if (lane == 0) {
    int dnode = ei[E + e];
    p = off[dnode] + atomicAdd(&cursor[dnode], 1);
    spd[p] = make_int2(ei[e], dnode);
  }
  p = __shfl(p, 0, 32);
  float4 v = *reinterpret_cast<const float4*>(ea + (size_t)e * D + lane * 4);
  reinterpret_cast<unsigned*>(eap)[(size_t)p * 32 + lane] = f32x4_to_fp8(v);
}

// one-time: bf16 shadow of x_in
__global__ __launch_bounds__(256) void conv_x_kernel(const float* __restrict__ x,
                                                     unsigned short* __restrict__ xbf,
                                                     long long n8) {
  long long t = (long long)blockIdx.x * 256 + threadIdx.x;
  if (t >= n8) return;
  float4 v0 = reinterpret_cast<const float4*>(x)[t * 2];
  float4 v1 = reinterpret_cast<const float4*>(x)[t * 2 + 1];
  ushort4 o0, o1;
  o0.x = f2bf(v0.x); o0.y = f2bf(v0.y); o0.z = f2bf(v0.z); o0.w = f2bf(v0.w);
  o1.x = f2bf(v1.x); o1.y = f2bf(v1.y); o1.z = f2bf(v1.z); o1.w = f2bf(v1.w);
  reinterpret_cast<ushort4*>(xbf)[t * 2] = o0;
  reinterpret_cast<ushort4*>(xbf)[t * 2 + 1] = o1;
}

// ---------------- one-time: pack weights into B-fragment order, hi/lo bf16 ----------------
__global__ void pack_w_kernel(const float* __restrict__ W1, const float* __restrict__ W2,
                              unsigned short* __restrict__ pk) {
  int c = blockIdx.x;
  const float* Ws[2] = {W1 + (size_t)c * D * D, W2 + (size_t)c * D * D};
  unsigned short* base = pk + (size_t)c * 4 * D * D;
  for (int t = threadIdx.x; t < 2048; t += blockDim.x) {
    int ct = t >> 8, ks = (t >> 6) & 3, l = t & 63;
    int col = ct * 16 + (l & 15);
    int krow = ks * 32 + ((l >> 4) & 3) * 8;
    for (int w = 0; w < 2; ++w) {
      unsigned short* hi = base + (size_t)w * 2 * D * D;
      unsigned short* lo = hi + D * D;
      const float* W = Ws[w];
      for (int i = 0; i < 8; ++i) {
        float v = W[(size_t)(krow + i) * D + col];
        unsigned short hb = f2bf(v);
        hi[(size_t)t * 8 + i] = hb;
        lo[(size_t)t * 8 + i] = f2bf(v - bf2f(hb));
      }
    }
  }
}

// ---------------- fused per-layer: edge-parallel gather + MLP + epilogue ----------------
__global__ __launch_bounds__(256, 4) void layer_kernel(
    const float* __restrict__ x, const unsigned short* __restrict__ xbf,
    const unsigned char* __restrict__ eap,
    const int* __restrict__ off, const int2* __restrict__ spd,
    const float* __restrict__ epsp,
    const unsigned short* __restrict__ wpk,   // w1hi|w1lo|w2hi|w2lo
    const float* __restrict__ b1, const float* __restrict__ b2,
    const float* __restrict__ mask,
    const float* __restrict__ gamma, const float* __restrict__ beta,
    const float* __restrict__ rmean, const float* __restrict__ rvar,
    const float* __restrict__ x_in, float* __restrict__ out,
    unsigned short* __restrict__ xbf_out,
    int N, int is_last) {
  __shared__ __align__(16) float hacc[BM * LDPF];  // 33792 B; t_hi/ys alias after barriers
  unsigned short* t_hi = reinterpret_cast<unsigned short*>(hacc);
  float* ys = hacc;

  const int tid = threadIdx.x;
  const int r0 = blockIdx.x * BM;
  const int rend = min(r0 + BM, N);
  const float one_eps = 1.0f + epsp[0];

  // zero hacc
  for (int j = tid; j < BM * LDPF / 4; j += 256)
    reinterpret_cast<float4*>(hacc)[j] = make_float4(0.f, 0.f, 0.f, 0.f);
  __syncthreads();

  // ---- phase 1: edge-parallel gather; wave owns a contiguous chunk, register
  //      accumulation per dst segment, native ds_add_f32 flush at boundaries ----
  {
    const int wv = tid >> 6;
    const int l = tid & 63;
    const int c2 = l * 2;               // lane owns cols c2, c2+1
    const int ebeg = off[r0], eend = off[rend];
    const int ne = eend - ebeg;
    const int chunk = (ne + 3) >> 2;
    const int cb = ebeg + wv * chunk;
    const int ce = min(cb + chunk, eend);
    float a0 = 0.f, a1 = 0.f;
    int cur = -1;

#define FLUSH()                                                        \
    if (cur >= 0) {                                                    \
      unsafeAtomicAdd(&hacc[(cur - r0) * LDPF + c2], a0);              \
      unsafeAtomicAdd(&hacc[(cur - r0) * LDPF + c2 + 1], a1);          \
    }
#define PROC(sd, xx, ee)                                               \
    {                                                                  \
      if (sd.y != cur) { FLUSH(); a0 = 0.f; a1 = 0.f; cur = sd.y; }    \
      f32x2 ep = __builtin_amdgcn_cvt_pk_f32_fp8((int)(unsigned)(ee), false); \
      a0 += fmaxf(bf2f((unsigned short)((xx) & 0xffff)) + ep[0], 0.f); \
      a1 += fmaxf(bf2f((unsigned short)((xx) >> 16)) + ep[1], 0.f);    \
    }

    for (int i = cb; i < ce; i += 4) {
      int nn = ce - i;
      int2 sd0, sd1, sd2, sd3;
      unsigned xx0 = 0, xx1 = 0, xx2 = 0, xx3 = 0;
      unsigned short e0 = 0, e1 = 0, e2 = 0, e3 = 0;
      sd0 = spd[i];
      if (nn > 1) sd1 = spd[i + 1];
      if (nn > 2) sd2 = spd[i + 2];
      if (nn > 3) sd3 = spd[i + 3];
      xx0 = *reinterpret_cast<const unsigned*>(xbf + (size_t)sd0.x * D + c2);
      e0 = *reinterpret_cast<const unsigned short*>(eap + (size_t)i * D + c2);
      if (nn > 1) {
        xx1 = *reinterpret_cast<const unsigned*>(xbf + (size_t)sd1.x * D + c2);
        e1 = *reinterpret_cast<const unsigned short*>(eap + (size_t)(i + 1) * D + c2);
      }
      if (nn > 2) {
        xx2 = *reinterpret_cast<const unsigned*>(xbf + (size_t)sd2.x * D + c2);
        e2 = *reinterpret_cast<const unsigned short*>(eap + (size_t)(i + 2) * D + c2);
      }
      if (nn > 3) {
        xx3 = *reinterpret_cast<const unsigned*>(xbf + (size_t)sd3.x * D + c2);
        e3 = *reinterpret_cast<const unsigned short*>(eap + (size_t)(i + 3) * D + c2);
      }
      PROC(sd0, xx0, e0);
      if (nn > 1) PROC(sd1, xx1, e1);
      if (nn > 2) PROC(sd2, xx2, e2);
      if (nn > 3) PROC(sd3, xx3, e3);
    }
    FLUSH();
#undef PROC
#undef FLUSH
  }
  __syncthreads();  // barrier: all gather flushes done

  // ---- h += (1+eps) * x (own elements, no races) ----
  for (int j = tid; j < BM * 32; j += 256) {
    int row = j >> 5, c4 = j & 31, gr = r0 + row;
    if (gr < N) {
      float4 xv = *reinterpret_cast<const float4*>(x + (size_t)gr * D + c4 * 4);
      float* hp = hacc + row * LDPF + c4 * 4;
      hp[0] += one_eps * xv.x;
      hp[1] += one_eps * xv.y;
      hp[2] += one_eps * xv.z;
      hp[3] += one_eps * xv.w;
    }
  }
  __syncthreads();  // barrier: h complete

  const int l = tid & 63;
  const int wave = tid >> 6;
  const int wm = wave >> 1;   // row half (32 rows)
  const int wn = wave & 1;    // col half (64 cols)
  const int cl = l & 15;
  const int kq = l >> 4;      // 0..3

  // ---- GEMM1: T = relu(h @ W1 + b1), 3-term split, regs-first ----
  f32x4 acc1[2][4];
  {
    s16x8 ahi[2][4], alo[2][4];
#pragma unroll
    for (int rt = 0; rt < 2; ++rt) {
      int row = wm * 32 + rt * 16 + cl;
#pragma unroll
      for (int ks = 0; ks < 4; ++ks) {
        const float* p = hacc + row * LDPF + ks * 32 + kq * 8;
        float4 v0 = *reinterpret_cast<const float4*>(p);
        float4 v1 = *reinterpret_cast<const float4*>(p + 4);
        float vv[8] = {v0.x, v0.y, v0.z, v0.w, v1.x, v1.y, v1.z, v1.w};
        s16x8 hi8, lo8;
#pragma unroll
        for (int q = 0; q < 8; ++q) {
          unsigned short hb = f2bf(vv[q]);
          hi8[q] = (short)hb;
          lo8[q] = (short)f2bf(vv[q] - bf2f(hb));
        }
        ahi[rt][ks] = hi8;
        alo[rt][ks] = lo8;
      }
    }
    const s16x8* w1h = reinterpret_cast<const s16x8*>(wpk);
    const s16x8* w1l = reinterpret_cast<const s16x8*>(wpk + D * D);
#pragma unroll
    for (int ct = 0; ct < 4; ++ct) {
      int gct = wn * 4 + ct;
      f32x4 a0 = {0.f, 0.f, 0.f, 0.f};
      f32x4 a1 = {0.f, 0.f, 0.f, 0.f};
#pragma unroll
      for (int ks = 0; ks < 4; ++ks) {
        s16x8 bh = w1h[(gct * 4 + ks) * 64 + l];
        s16x8 bl = w1l[(gct * 4 + ks) * 64 + l];
        a0 = __builtin_amdgcn_mfma_f32_16x16x32_bf16(ahi[0][ks], bh, a0, 0, 0, 0);
        a0 = __builtin_amdgcn_mfma_f32_16x16x32_bf16(alo[0][ks], bh, a0, 0, 0, 0);
        a0 = __builtin_amdgcn_mfma_f32_16x16x32_bf16(ahi[0][ks], bl, a0, 0, 0, 0);
        a1 = __builtin_amdgcn_mfma_f32_16x16x32_bf16(ahi[1][ks], bh, a1, 0, 0, 0);
        a1 = __builtin_amdgcn_mfma_f32_16x16x32_bf16(alo[1][ks], bh, a1, 0, 0, 0);
        a1 = __builtin_amdgcn_mfma_f32_16x16x32_bf16(ahi[1][ks], bl, a1, 0, 0, 0);
      }
      acc1[0][ct] = a0;
      acc1[1][ct] = a1;
    }
  }
  __syncthreads();  // barrier: all h reads retired -> region reusable as t_hi

  // write T = relu(acc1 + b1) as bf16 into t_hi
#pragma unroll
  for (int ct = 0; ct < 4; ++ct) {
    int gct = wn * 4 + ct;
    float bv = b1[gct * 16 + cl];
#pragma unroll
    for (int i = 0; i < 4; ++i) {
      t_hi[(wm * 32 + kq * 4 + i) * LDSH + gct * 16 + cl] = f2bf(fmaxf(acc1[0][ct][i] + bv, 0.f));
      t_hi[(wm * 32 + 16 + kq * 4 + i) * LDSH + gct * 16 + cl] = f2bf(fmaxf(acc1[1][ct][i] + bv, 0.f));
    }
  }
  __syncthreads();  // barrier: T complete

  // ---- GEMM2: Y = T @ W2, 2-term split, regs-first ----
  f32x4 acc2[2][4];
  {
    s16x8 thi[2][4];
#pragma unroll
    for (int rt = 0; rt < 2; ++rt) {
      int row = wm * 32 + rt * 16 + cl;
#pragma unroll
      for (int ks = 0; ks < 4; ++ks)
        thi[rt][ks] = *reinterpret_cast<const s16x8*>(t_hi + row * LDSH + ks * 32 + kq * 8);
    }
    const s16x8* w2h = reinterpret_cast<const s16x8*>(wpk + 2 * D * D);
    const s16x8* w2l = reinterpret_cast<const s16x8*>(wpk + 3 * D * D);
#pragma unroll
    for (int ct = 0; ct < 4; ++ct) {
      int gct = wn * 4 + ct;
      f32x4 a0 = {0.f, 0.f, 0.f, 0.f};
      f32x4 a1 = {0.f, 0.f, 0.f, 0.f};
#pragma unroll
      for (int ks = 0; ks < 4; ++ks) {
        s16x8 bh = w2h[(gct * 4 + ks) * 64 + l];
        s16x8 bl = w2l[(gct * 4 + ks) * 64 + l];
        a0 = __builtin_amdgcn_mfma_f32_16x16x32_bf16(thi[0][ks], bh, a0, 0, 0, 0);
        a0 = __builtin_amdgcn_mfma_f32_16x16x32_bf16(thi[0][ks], bl, a0, 0, 0, 0);
        a1 = __builtin_amdgcn_mfma_f32_16x16x32_bf16(thi[1][ks], bh, a1, 0, 0, 0);
        a1 = __builtin_amdgcn_mfma_f32_16x16x32_bf16(thi[1][ks], bl, a1, 0, 0, 0);
      }
      acc2[0][ct] = a0;
      acc2[1][ct] = a1;
    }
  }
  __syncthreads();  // barrier: all T reads retired -> region reusable as ys

#pragma unroll
  for (int ct = 0; ct < 4; ++ct) {
    int gct = wn * 4 + ct;
#pragma unroll
    for (int i = 0; i < 4; ++i) {
      ys[(wm * 32 + kq * 4 + i) * LDPF + gct * 16 + cl] = acc2[0][ct][i];
      ys[(wm * 32 + 16 + kq * 4 + i) * LDPF + gct * 16 + cl] = acc2[1][ct][i];
    }
  }
  __syncthreads();  // barrier: Y complete

  // ---- epilogue: v = mask*(Y+b2) + x ; BN ; final relu+residual ; bf16 shadow ----
  for (int j = tid; j < BM * 32; j += 256) {
    int row = j >> 5, c4 = j & 31;
    int gr = r0 + row;
    if (gr >= N) continue;
    float4 yv = *reinterpret_cast<const float4*>(ys + row * LDPF + c4 * 4);
    float4 b2v = reinterpret_cast<const float4*>(b2)[c4];
    float4 gv  = reinterpret_cast<const float4*>(gamma)[c4];
    float4 bv  = reinterpret_cast<const float4*>(beta)[c4];
    float4 rmv = reinterpret_cast<const float4*>(rmean)[c4];
    float4 rvv = reinterpret_cast<const float4*>(rvar)[c4];
    float4 sc;
    sc.x = gv.x * rsqrtf(rvv.x + 1e-5f);
    sc.y = gv.y * rsqrtf(rvv.y + 1e-5f);
    sc.z = gv.z * rsqrtf(rvv.z + 1e-5f);
    sc.w = gv.w * rsqrtf(rvv.w + 1e-5f);
    float mk = mask[gr];
    float4 xv = *reinterpret_cast<const float4*>(x + (size_t)gr * D + c4 * 4);
    float4 v;
    v.x = fmaf(mk, yv.x + b2v.x, xv.x);
    v.y = fmaf(mk, yv.y + b2v.y, xv.y);
    v.z = fmaf(mk, yv.z + b2v.z, xv.z);
    v.w = fmaf(mk, yv.w + b2v.w, xv.w);
    v.x = fmaf(v.x - rmv.x, sc.x, bv.x);
    v.y = fmaf(v.y - rmv.y, sc.y, bv.y);
    v.z = fmaf(v.z - rmv.z, sc.z, bv.z);
    v.w = fmaf(v.w - rmv.w, sc.w, bv.w);
    if (is_last) {
      float4 xi = *reinterpret_cast<const float4*>(x_in + (size_t)gr * D + c4 * 4);
      v.x = xi.x + fmaxf(v.x, 0.f);
      v.y = xi.y + fmaxf(v.y, 0.f);
      v.z = xi.z + fmaxf(v.z, 0.f);
      v.w = xi.w + fmaxf(v.w, 0.f);
    } else {
      ushort4 o;
      o.x = f2bf(v.x); o.y = f2bf(v.y); o.z = f2bf(v.z); o.w = f2bf(v.w);
      *reinterpret_cast<ushort4*>(xbf_out + (size_t)gr * D + c4 * 4) = o;
    }
    *reinterpret_cast<float4*>(out + (size_t)gr * D + c4 * 4) = v;
  }
}

static inline char* align_up(char* p, size_t a) {
  return (char*)(((size_t)p + a - 1) & ~(a - 1));
}

extern "C" void kernel_launch(void* const* d_in, const int* in_sizes, int n_in,
                              void* d_out, int out_size, void* d_ws, size_t ws_size,
                              hipStream_t stream) {
  const float* x_in  = (const float*)d_in[0];
  const int*   ei    = (const int*)d_in[1];
  const float* ea    = (const float*)d_in[2];
  const float* masks = (const float*)d_in[3];
  const float* W1    = (const float*)d_in[4];
  const float* b1    = (const float*)d_in[5];
  const float* W2    = (const float*)d_in[6];
  const float* b2    = (const float*)d_in[7];
  const float* eps   = (const float*)d_in[8];
  const float* gamma = (const float*)d_in[9];
  const float* beta  = (const float*)d_in[10];
  const float* rmean = (const float*)d_in[11];
  const float* rvar  = (const float*)d_in[12];
  const int N = in_sizes[0] / D;
  const int E = in_sizes[1] / 2;
  const int C = in_sizes[8];
  const int nb = (N + CHUNK - 1) / CHUNK;

  // workspace layout
  char* w = (char*)d_ws;
  float* xalt  = (float*)w;  w += (size_t)N * D * sizeof(float);
  int* deg     = (int*)w;    w += (size_t)N * sizeof(int);
  int* off     = (int*)w;    w += (size_t)(N + 1) * sizeof(int);
  int* cursor  = (int*)w;    w += (size_t)N * sizeof(int);
  int* partial = (int*)w;    w += (size_t)(nb + 1) * sizeof(int);
  w = align_up(w, 128);
  int2* spd    = (int2*)w;   w += (size_t)E * sizeof(int2);
  unsigned short* xbfA = (unsigned short*)w;  w += (size_t)N * D * sizeof(unsigned short);
  unsigned short* xbfB = (unsigned short*)w;  w += (size_t)N * D * sizeof(unsigned short);
  unsigned short* wpk  = (unsigned short*)w;  w += (size_t)C * 4 * D * D * sizeof(unsigned short);
  w = align_up(w, 128);
  unsigned char* eap = (unsigned char*)w;     // E * 128 bytes (fp8 e4m3)

  // ---- one-time: CSR + permuted fp8 edge_attr + packed weights + bf16 x_in ----
  hipMemsetAsync(deg, 0, (size_t)N * sizeof(int), stream);
  hipMemsetAsync(cursor, 0, (size_t)N * sizeof(int), stream);
  hist_kernel<<<(E + 255) / 256, 256, 0, stream>>>(ei, deg, E);
  partial_kernel<<<nb, 256, 0, stream>>>(deg, partial, N);
  scanpart_kernel<<<1, 1024, 0, stream>>>(partial, nb);
  chunkscan_kernel<<<nb, 256, 0, stream>>>(deg, partial, off, N);
  scatter_conv_kernel<<<(E + 7) / 8, 256, 0, stream>>>(ei, ea, off, cursor, spd, eap, E);
  pack_w_kernel<<<C, 256, 0, stream>>>(W1, W2, wpk);
  long long n8 = (long long)N * D / 8;
  conv_x_kernel<<<(int)((n8 + 255) / 256), 256, 0, stream>>>(x_in, xbfA, n8);

  const int blocks = (N + BM - 1) / BM;
  const float* xc = x_in;
  const unsigned short* xbf_cur = xbfA;
  for (int c = 0; c < C; ++c) {
    float* dst = (((C - 1 - c) & 1) == 0) ? (float*)d_out : xalt;
    unsigned short* xbf_next = (xbf_cur == xbfA) ? xbfB : xbfA;
    layer_kernel<<<blocks, 256, 0, stream>>>(
        xc, xbf_cur, eap, off, spd, eps + c,
        wpk + (size_t)c * 4 * D * D,
        b1 + (size_t)c * D, b2 + (size_t)c * D,
        masks + (size_t)c * N,
        gamma + (size_t)c * D, beta + (size_t)c * D,
        rmean + (size_t)c * D, rvar + (size_t)c * D,
        x_in, dst, xbf_next, N, (c == C - 1) ? 1 : 0);
    xc = dst;
    xbf_cur = xbf_next;
  }
}

// Round 9
// 551.010 us; speedup vs baseline: 1.2814x; 1.2814x over previous
//
#include <hip/hip_runtime.h>
#include <cstddef>

#define D 128
#define CHUNK 1024
#define BM 64        // rows per layer block (4 waves; 2M x 2N wave grid)
#define LDSH 136     // short row stride for h_hi/h_lo/t_hi (272B)
#define LDPF 132     // f32 row stride for ys (528B)

typedef __attribute__((ext_vector_type(8))) short s16x8;
typedef __attribute__((ext_vector_type(8))) unsigned short u16x8;
typedef __attribute__((ext_vector_type(4))) float f32x4;
typedef __attribute__((ext_vector_type(2))) float f32x2;

__device__ __forceinline__ unsigned short f2bf(float f) {
  unsigned u = __builtin_bit_cast(unsigned, f);
  u += 0x7FFFu + ((u >> 16) & 1u);
  return (unsigned short)(u >> 16);
}
__device__ __forceinline__ float bf2f(unsigned short h) {
  unsigned u = ((unsigned)h) << 16;
  return __builtin_bit_cast(float, u);
}
__device__ __forceinline__ unsigned f32x4_to_fp8(float4 v) {
  int r = __builtin_amdgcn_cvt_pk_fp8_f32(v.x, v.y, 0, false);
  r = __builtin_amdgcn_cvt_pk_fp8_f32(v.z, v.w, r, true);
  return (unsigned)r;
}
__device__ __forceinline__ void fp8x4_to_f32(unsigned u, float* o) {
  f32x2 lo = __builtin_amdgcn_cvt_pk_f32_fp8((int)u, false);
  f32x2 hi = __builtin_amdgcn_cvt_pk_f32_fp8((int)u, true);
  o[0] = lo[0]; o[1] = lo[1]; o[2] = hi[0]; o[3] = hi[1];
}

// ---------------- CSR build (once per call) ----------------
__global__ __launch_bounds__(256) void hist_kernel(const int* __restrict__ ei,
                                                   int* __restrict__ deg, int E) {
  int e = blockIdx.x * 256 + threadIdx.x;
  if (e < E) atomicAdd(&deg[ei[E + e]], 1);
}

__global__ __launch_bounds__(256) void partial_kernel(const int* __restrict__ deg,
                                                      int* __restrict__ partial, int N) {
  __shared__ int s[256];
  int base = blockIdx.x * CHUNK;
  int sum = 0;
  for (int j = threadIdx.x; j < CHUNK; j += 256) {
    int idx = base + j;
    sum += (idx < N) ? deg[idx] : 0;
  }
  s[threadIdx.x] = sum;
  __syncthreads();
  for (int ofs = 128; ofs > 0; ofs >>= 1) {
    if (threadIdx.x < ofs) s[threadIdx.x] += s[threadIdx.x + ofs];
    __syncthreads();
  }
  if (threadIdx.x == 0) partial[blockIdx.x] = s[0];
}

__global__ __launch_bounds__(1024) void scanpart_kernel(int* partial, int nb) {
  __shared__ int s[1024];
  int tid = threadIdx.x;
  int v = (tid < nb) ? partial[tid] : 0;
  s[tid] = v;
  __syncthreads();
  for (int o = 1; o < 1024; o <<= 1) {
    int t = (tid >= o) ? s[tid - o] : 0;
    __syncthreads();
    s[tid] += t;
    __syncthreads();
  }
  if (tid < nb) partial[tid] = s[tid] - v;
}

__global__ __launch_bounds__(256) void chunkscan_kernel(const int* __restrict__ deg,
                                                        const int* __restrict__ partial,
                                                        int* __restrict__ off, int N) {
  __shared__ int ws[4];
  int base = blockIdx.x * CHUNK;
  int i0 = base + threadIdx.x * 4;
  int d[4];
  int s = 0;
#pragma unroll
  for (int k = 0; k < 4; ++k) {
    d[k] = (i0 + k < N) ? deg[i0 + k] : 0;
    s += d[k];
  }
  int lane = threadIdx.x & 63;
  int incl = s;
  for (int o = 1; o < 64; o <<= 1) {
    int v = __shfl_up(incl, o, 64);
    if (lane >= o) incl += v;
  }
  int wave = threadIdx.x >> 6;
  if (lane == 63) ws[wave] = incl;
  __syncthreads();
  int wofs = 0;
  for (int w = 0; w < wave; ++w) wofs += ws[w];
  int run = partial[blockIdx.x] + wofs + (incl - s);
#pragma unroll
  for (int k = 0; k < 4; ++k) {
    int idx = i0 + k;
    if (idx < N) {
      off[idx] = run;
      run += d[k];
      if (idx == N - 1) off[N] = run;
    }
  }
}

// scatter + fp8 convert fused: half-wave per edge, ea read is sequential
__global__ __launch_bounds__(256) void scatter_conv_kernel(
    const int* __restrict__ ei, const float* __restrict__ ea,
    const int* __restrict__ off, int* __restrict__ cursor,
    int* __restrict__ sperm, unsigned char* __restrict__ eap, int E) {
  int t = blockIdx.x * 256 + threadIdx.x;
  int lane = t & 31;
  int e = t >> 5;
  if (e >= E) return;
  int p = 0;
  if (lane == 0) {
    int dnode = ei[E + e];
    p = off[dnode] + atomicAdd(&cursor[dnode], 1);
    sperm[p] = ei[e];
  }
  p = __shfl(p, 0, 32);
  float4 v = *reinterpret_cast<const float4*>(ea + (size_t)e * D + lane * 4);
  reinterpret_cast<unsigned*>(eap)[(size_t)p * 32 + lane] = f32x4_to_fp8(v);
}

// one-time: bf16 shadow of x_in
__global__ __launch_bounds__(256) void conv_x_kernel(const float* __restrict__ x,
                                                     unsigned short* __restrict__ xbf,
                                                     long long n8) {
  long long t = (long long)blockIdx.x * 256 + threadIdx.x;
  if (t >= n8) return;
  float4 v0 = reinterpret_cast<const float4*>(x)[t * 2];
  float4 v1 = reinterpret_cast<const float4*>(x)[t * 2 + 1];
  ushort4 o0, o1;
  o0.x = f2bf(v0.x); o0.y = f2bf(v0.y); o0.z = f2bf(v0.z); o0.w = f2bf(v0.w);
  o1.x = f2bf(v1.x); o1.y = f2bf(v1.y); o1.z = f2bf(v1.z); o1.w = f2bf(v1.w);
  reinterpret_cast<ushort4*>(xbf)[t * 2] = o0;
  reinterpret_cast<ushort4*>(xbf)[t * 2 + 1] = o1;
}

// ---------------- one-time: pack weights into B-fragment order, hi/lo bf16 ----------------
__global__ void pack_w_kernel(const float* __restrict__ W1, const float* __restrict__ W2,
                              unsigned short* __restrict__ pk) {
  int c = blockIdx.x;
  const float* Ws[2] = {W1 + (size_t)c * D * D, W2 + (size_t)c * D * D};
  unsigned short* base = pk + (size_t)c * 4 * D * D;
  for (int t = threadIdx.x; t < 2048; t += blockDim.x) {
    int ct = t >> 8, ks = (t >> 6) & 3, l = t & 63;
    int col = ct * 16 + (l & 15);
    int krow = ks * 32 + ((l >> 4) & 3) * 8;
    for (int w = 0; w < 2; ++w) {
      unsigned short* hi = base + (size_t)w * 2 * D * D;
      unsigned short* lo = hi + D * D;
      const float* W = Ws[w];
      for (int i = 0; i < 8; ++i) {
        float v = W[(size_t)(krow + i) * D + col];
        unsigned short hb = f2bf(v);
        hi[(size_t)t * 8 + i] = hb;
        lo[(size_t)t * 8 + i] = f2bf(v - bf2f(hb));
      }
    }
  }
}

// ---------------- fused per-layer: dst-parallel gather (4-deep ILP) + MLP + epilogue ----------------
__global__ __launch_bounds__(256, 4) void layer_kernel(
    const float* __restrict__ x, const unsigned short* __restrict__ xbf,
    const unsigned char* __restrict__ eap,
    const int* __restrict__ off, const int* __restrict__ sperm,
    const float* __restrict__ epsp,
    const unsigned short* __restrict__ wpk,   // w1hi|w1lo|w2hi|w2lo
    const float* __restrict__ b1, const float* __restrict__ b2,
    const float* __restrict__ mask,
    const float* __restrict__ gamma, const float* __restrict__ beta,
    const float* __restrict__ rmean, const float* __restrict__ rvar,
    const float* __restrict__ x_in, float* __restrict__ out,
    unsigned short* __restrict__ xbf_out,
    int N, int is_last) {
  __shared__ __align__(16) char smem[2 * BM * LDSH * 2];  // 34816 B
  unsigned short* h_hi = reinterpret_cast<unsigned short*>(smem);
  unsigned short* h_lo = h_hi + BM * LDSH;
  unsigned short* t_hi = h_hi;                 // alias, valid after barrier 2
  float* ys = reinterpret_cast<float*>(smem);  // alias, valid after barrier 4

  const int tid = threadIdx.x;
  const int r0 = blockIdx.x * BM;
  const float one_eps = 1.0f + epsp[0];

  // ---- phase 1: gather-aggregate (quarter-wave per row, 4-deep batched loads) ----
  {
    const int qw = tid >> 4;        // 0..15
    const int l16 = tid & 15;       // 8 elems per lane
#pragma unroll
    for (int it = 0; it < 4; ++it) {
      int row = it * 16 + qw;
      int gr = r0 + row;
      unsigned short* ph = h_hi + row * LDSH + l16 * 8;
      unsigned short* pl = h_lo + row * LDSH + l16 * 8;
      if (gr >= N) {
        u16x8 z = {0, 0, 0, 0, 0, 0, 0, 0};
        *reinterpret_cast<u16x8*>(ph) = z;
        *reinterpret_cast<u16x8*>(pl) = z;
        continue;
      }
      int beg = off[gr], end = off[gr + 1];
      float acc[8] = {0.f, 0.f, 0.f, 0.f, 0.f, 0.f, 0.f, 0.f};
      for (int i = beg; i < end; i += 4) {
        int n = end - i;
        // clamp tail indices in-range (loads duplicate, accumulation is guarded)
        int i1 = (n > 1) ? i + 1 : i;
        int i2 = (n > 2) ? i + 2 : i;
        int i3 = (n > 3) ? i + 3 : i;
        int s0 = sperm[i], s1 = sperm[i1], s2 = sperm[i2], s3 = sperm[i3];
        u16x8 xv0 = *reinterpret_cast<const u16x8*>(xbf + (size_t)s0 * D + l16 * 8);
        u16x8 xv1 = *reinterpret_cast<const u16x8*>(xbf + (size_t)s1 * D + l16 * 8);
        u16x8 xv2 = *reinterpret_cast<const u16x8*>(xbf + (size_t)s2 * D + l16 * 8);
        u16x8 xv3 = *reinterpret_cast<const u16x8*>(xbf + (size_t)s3 * D + l16 * 8);
        uint2 eu0 = *reinterpret_cast<const uint2*>(eap + (size_t)i * D + l16 * 8);
        uint2 eu1 = *reinterpret_cast<const uint2*>(eap + (size_t)i1 * D + l16 * 8);
        uint2 eu2 = *reinterpret_cast<const uint2*>(eap + (size_t)i2 * D + l16 * 8);
        uint2 eu3 = *reinterpret_cast<const uint2*>(eap + (size_t)i3 * D + l16 * 8);
#define ACC(xv, eu)                                                      \
        {                                                                \
          float ev[8];                                                   \
          fp8x4_to_f32((eu).x, ev);                                      \
          fp8x4_to_f32((eu).y, ev + 4);                                  \
          _Pragma("unroll")                                              \
          for (int q = 0; q < 8; ++q)                                    \
            acc[q] += fmaxf(bf2f((unsigned short)(xv)[q]) + ev[q], 0.f); \
        }
        ACC(xv0, eu0);
        if (n > 1) ACC(xv1, eu1);
        if (n > 2) ACC(xv2, eu2);
        if (n > 3) ACC(xv3, eu3);
#undef ACC
      }
      const float* xd = x + (size_t)gr * D + l16 * 8;
      float4 x0 = *reinterpret_cast<const float4*>(xd);
      float4 x1 = *reinterpret_cast<const float4*>(xd + 4);
      float hv[8];
      hv[0] = fmaf(one_eps, x0.x, acc[0]); hv[1] = fmaf(one_eps, x0.y, acc[1]);
      hv[2] = fmaf(one_eps, x0.z, acc[2]); hv[3] = fmaf(one_eps, x0.w, acc[3]);
      hv[4] = fmaf(one_eps, x1.x, acc[4]); hv[5] = fmaf(one_eps, x1.y, acc[5]);
      hv[6] = fmaf(one_eps, x1.z, acc[6]); hv[7] = fmaf(one_eps, x1.w, acc[7]);
      u16x8 hi8, lo8;
#pragma unroll
      for (int q = 0; q < 8; ++q) {
        unsigned short hb = f2bf(hv[q]);
        hi8[q] = hb;
        lo8[q] = f2bf(hv[q] - bf2f(hb));
      }
      *reinterpret_cast<u16x8*>(ph) = hi8;
      *reinterpret_cast<u16x8*>(pl) = lo8;
    }
  }
  __syncthreads();  // barrier 1: h complete

  const int l = tid & 63;
  const int wave = tid >> 6;
  const int wm = wave >> 1;   // row half (32 rows)
  const int wn = wave & 1;    // col half (64 cols)
  const int cl = l & 15;
  const int kq = l >> 4;      // 0..3

  // ---- GEMM1: T = relu(h @ W1 + b1), 3-term split, regs-first ----
  f32x4 acc1[2][4];
  {
    s16x8 ahi[2][4], alo[2][4];
#pragma unroll
    for (int rt = 0; rt < 2; ++rt) {
      int row = wm * 32 + rt * 16 + cl;
#pragma unroll
      for (int ks = 0; ks < 4; ++ks) {
        ahi[rt][ks] = *reinterpret_cast<const s16x8*>(h_hi + row * LDSH + ks * 32 + kq * 8);
        alo[rt][ks] = *reinterpret_cast<const s16x8*>(h_lo + row * LDSH + ks * 32 + kq * 8);
      }
    }
    const s16x8* w1h = reinterpret_cast<const s16x8*>(wpk);
    const s16x8* w1l = reinterpret_cast<const s16x8*>(wpk + D * D);
#pragma unroll
    for (int ct = 0; ct < 4; ++ct) {
      int gct = wn * 4 + ct;
      f32x4 a0 = {0.f, 0.f, 0.f, 0.f};
      f32x4 a1 = {0.f, 0.f, 0.f, 0.f};
#pragma unroll
      for (int ks = 0; ks < 4; ++ks) {
        s16x8 bh = w1h[(gct * 4 + ks) * 64 + l];
        s16x8 bl = w1l[(gct * 4 + ks) * 64 + l];
        a0 = __builtin_amdgcn_mfma_f32_16x16x32_bf16(ahi[0][ks], bh, a0, 0, 0, 0);
        a0 = __builtin_amdgcn_mfma_f32_16x16x32_bf16(alo[0][ks], bh, a0, 0, 0, 0);
        a0 = __builtin_amdgcn_mfma_f32_16x16x32_bf16(ahi[0][ks], bl, a0, 0, 0, 0);
        a1 = __builtin_amdgcn_mfma_f32_16x16x32_bf16(ahi[1][ks], bh, a1, 0, 0, 0);
        a1 = __builtin_amdgcn_mfma_f32_16x16x32_bf16(alo[1][ks], bh, a1, 0, 0, 0);
        a1 = __builtin_amdgcn_mfma_f32_16x16x32_bf16(ahi[1][ks], bl, a1, 0, 0, 0);
      }
      acc1[0][ct] = a0;
      acc1[1][ct] = a1;
    }
  }
  __syncthreads();  // barrier 2: all h reads retired -> h region reusable as t_hi

  // write T = relu(acc1 + b1) as bf16 into t_hi
#pragma unroll
  for (int ct = 0; ct < 4; ++ct) {
    int gct = wn * 4 + ct;
    float bv = b1[gct * 16 + cl];
#pragma unroll
    for (int i = 0; i < 4; ++i) {
      t_hi[(wm * 32 + kq * 4 + i) * LDSH + gct * 16 + cl] = f2bf(fmaxf(acc1[0][ct][i] + bv, 0.f));
      t_hi[(wm * 32 + 16 + kq * 4 + i) * LDSH + gct * 16 + cl] = f2bf(fmaxf(acc1[1][ct][i] + bv, 0.f));
    }
  }
  __syncthreads();  // barrier 3: T complete

  // ---- GEMM2: Y = T @ W2, 2-term split, regs-first ----
  f32x4 acc2[2][4];
  {
    s16x8 thi[2][4];
#pragma unroll
    for (int rt = 0; rt < 2; ++rt) {
      int row = wm * 32 + rt * 16 + cl;
#pragma unroll
      for (int ks = 0; ks < 4; ++ks)
        thi[rt][ks] = *reinterpret_cast<const s16x8*>(t_hi + row * LDSH + ks * 32 + kq * 8);
    }
    const s16x8* w2h = reinterpret_cast<const s16x8*>(wpk + 2 * D * D);
    const s16x8* w2l = reinterpret_cast<const s16x8*>(wpk + 3 * D * D);
#pragma unroll
    for (int ct = 0; ct < 4; ++ct) {
      int gct = wn * 4 + ct;
      f32x4 a0 = {0.f, 0.f, 0.f, 0.f};
      f32x4 a1 = {0.f, 0.f, 0.f, 0.f};
#pragma unroll
      for (int ks = 0; ks < 4; ++ks) {
        s16x8 bh = w2h[(gct * 4 + ks) * 64 + l];
        s16x8 bl = w2l[(gct * 4 + ks) * 64 + l];
        a0 = __builtin_amdgcn_mfma_f32_16x16x32_bf16(thi[0][ks], bh, a0, 0, 0, 0);
        a0 = __builtin_amdgcn_mfma_f32_16x16x32_bf16(thi[0][ks], bl, a0, 0, 0, 0);
        a1 = __builtin_amdgcn_mfma_f32_16x16x32_bf16(thi[1][ks], bh, a1, 0, 0, 0);
        a1 = __builtin_amdgcn_mfma_f32_16x16x32_bf16(thi[1][ks], bl, a1, 0, 0, 0);
      }
      acc2[0][ct] = a0;
      acc2[1][ct] = a1;
    }
  }
  __syncthreads();  // barrier 4: all T reads retired -> region reusable as ys

#pragma unroll
  for (int ct = 0; ct < 4; ++ct) {
    int gct = wn * 4 + ct;
#pragma unroll
    for (int i = 0; i < 4; ++i) {
      ys[(wm * 32 + kq * 4 + i) * LDPF + gct * 16 + cl] = acc2[0][ct][i];
      ys[(wm * 32 + 16 + kq * 4 + i) * LDPF + gct * 16 + cl] = acc2[1][ct][i];
    }
  }
  __syncthreads();  // barrier 5: Y complete

  // ---- epilogue: v = mask*(Y+b2) + x ; BN ; final relu+residual ; bf16 shadow ----
  for (int j = tid; j < BM * 32; j += 256) {
    int row = j >> 5, c4 = j & 31;
    int gr = r0 + row;
    if (gr >= N) continue;
    float4 yv = *reinterpret_cast<const float4*>(ys + row * LDPF + c4 * 4);
    float4 b2v = reinterpret_cast<const float4*>(b2)[c4];
    float4 gv  = reinterpret_cast<const float4*>(gamma)[c4];
    float4 bv  = reinterpret_cast<const float4*>(beta)[c4];
    float4 rmv = reinterpret_cast<const float4*>(rmean)[c4];
    float4 rvv = reinterpret_cast<const float4*>(rvar)[c4];
    float4 sc;
    sc.x = gv.x * rsqrtf(rvv.x + 1e-5f);
    sc.y = gv.y * rsqrtf(rvv.y + 1e-5f);
    sc.z = gv.z * rsqrtf(rvv.z + 1e-5f);
    sc.w = gv.w * rsqrtf(rvv.w + 1e-5f);
    float mk = mask[gr];
    float4 xv = *reinterpret_cast<const float4*>(x + (size_t)gr * D + c4 * 4);
    float4 v;
    v.x = fmaf(mk, yv.x + b2v.x, xv.x);
    v.y = fmaf(mk, yv.y + b2v.y, xv.y);
    v.z = fmaf(mk, yv.z + b2v.z, xv.z);
    v.w = fmaf(mk, yv.w + b2v.w, xv.w);
    v.x = fmaf(v.x - rmv.x, sc.x, bv.x);
    v.y = fmaf(v.y - rmv.y, sc.y, bv.y);
    v.z = fmaf(v.z - rmv.z, sc.z, bv.z);
    v.w = fmaf(v.w - rmv.w, sc.w, bv.w);
    if (is_last) {
      float4 xi = *reinterpret_cast<const float4*>(x_in + (size_t)gr * D + c4 * 4);
      v.x = xi.x + fmaxf(v.x, 0.f);
      v.y = xi.y + fmaxf(v.y, 0.f);
      v.z = xi.z + fmaxf(v.z, 0.f);
      v.w = xi.w + fmaxf(v.w, 0.f);
    } else {
      ushort4 o;
      o.x = f2bf(v.x); o.y = f2bf(v.y); o.z = f2bf(v.z); o.w = f2bf(v.w);
      *reinterpret_cast<ushort4*>(xbf_out + (size_t)gr * D + c4 * 4) = o;
    }
    *reinterpret_cast<float4*>(out + (size_t)gr * D + c4 * 4) = v;
  }
}

static inline char* align_up(char* p, size_t a) {
  return (char*)(((size_t)p + a - 1) & ~(a - 1));
}

extern "C" void kernel_launch(void* const* d_in, const int* in_sizes, int n_in,
                              void* d_out, int out_size, void* d_ws, size_t ws_size,
                              hipStream_t stream) {
  const float* x_in  = (const float*)d_in[0];
  const int*   ei    = (const int*)d_in[1];
  const float* ea    = (const float*)d_in[2];
  const float* masks = (const float*)d_in[3];
  const float* W1    = (const float*)d_in[4];
  const float* b1    = (const float*)d_in[5];
  const float* W2    = (const float*)d_in[6];
  const float* b2    = (const float*)d_in[7];
  const float* eps   = (const float*)d_in[8];
  const float* gamma = (const float*)d_in[9];
  const float* beta  = (const float*)d_in[10];
  const float* rmean = (const float*)d_in[11];
  const float* rvar  = (const float*)d_in[12];
  const int N = in_sizes[0] / D;
  const int E = in_sizes[1] / 2;
  const int C = in_sizes[8];
  const int nb = (N + CHUNK - 1) / CHUNK;

  // workspace layout
  char* w = (char*)d_ws;
  float* xalt  = (float*)w;  w += (size_t)N * D * sizeof(float);
  int* deg     = (int*)w;    w += (size_t)N * sizeof(int);
  int* off     = (int*)w;    w += (size_t)(N + 1) * sizeof(int);
  int* cursor  = (int*)w;    w += (size_t)N * sizeof(int);
  int* partial = (int*)w;    w += (size_t)(nb + 1) * sizeof(int);
  int* sperm   = (int*)w;    w += (size_t)E * sizeof(int);
  w = align_up(w, 128);
  unsigned short* xbfA = (unsigned short*)w;  w += (size_t)N * D * sizeof(unsigned short);
  unsigned short* xbfB = (unsigned short*)w;  w += (size_t)N * D * sizeof(unsigned short);
  unsigned short* wpk  = (unsigned short*)w;  w += (size_t)C * 4 * D * D * sizeof(unsigned short);
  w = align_up(w, 128);
  unsigned char* eap = (unsigned char*)w;     // E * 128 bytes (fp8 e4m3)

  // ---- one-time: CSR + permuted fp8 edge_attr + packed weights + bf16 x_in ----
  hipMemsetAsync(deg, 0, (size_t)N * sizeof(int), stream);
  hipMemsetAsync(cursor, 0, (size_t)N * sizeof(int), stream);
  hist_kernel<<<(E + 255) / 256, 256, 0, stream>>>(ei, deg, E);
  partial_kernel<<<nb, 256, 0, stream>>>(deg, partial, N);
  scanpart_kernel<<<1, 1024, 0, stream>>>(partial, nb);
  chunkscan_kernel<<<nb, 256, 0, stream>>>(deg, partial, off, N);
  scatter_conv_kernel<<<(E + 7) / 8, 256, 0, stream>>>(ei, ea, off, cursor, sperm, eap, E);
  pack_w_kernel<<<C, 256, 0, stream>>>(W1, W2, wpk);
  long long n8 = (long long)N * D / 8;
  conv_x_kernel<<<(int)((n8 + 255) / 256), 256, 0, stream>>>(x_in, xbfA, n8);

  const int blocks = (N + BM - 1) / BM;
  const float* xc = x_in;
  const unsigned short* xbf_cur = xbfA;
  for (int c = 0; c < C; ++c) {
    float* dst = (((C - 1 - c) & 1) == 0) ? (float*)d_out : xalt;
    unsigned short* xbf_next = (xbf_cur == xbfA) ? xbfB : xbfA;
    layer_kernel<<<blocks, 256, 0, stream>>>(
        xc, xbf_cur, eap, off, sperm, eps + c,
        wpk + (size_t)c * 4 * D * D,
        b1 + (size_t)c * D, b2 + (size_t)c * D,
        masks + (size_t)c * N,
        gamma + (size_t)c * D, beta + (size_t)c * D,
        rmean + (size_t)c * D, rvar + (size_t)c * D,
        x_in, dst, xbf_next, N, (c == C - 1) ? 1 : 0);
    xc = dst;
    xbf_cur = xbf_next;
  }
}

// Round 10
// 503.160 us; speedup vs baseline: 1.4032x; 1.0951x over previous
//
#include <hip/hip_runtime.h>
#include <cstddef>

#define D 128
#define CHUNK 1024
#define BM 64        // rows per layer block (4 waves; 2M x 2N wave grid)
#define LDSH 136     // short row stride for h/t/ys (272B, bank-safe)

typedef __attribute__((ext_vector_type(8))) short s16x8;
typedef __attribute__((ext_vector_type(8))) unsigned short u16x8;
typedef __attribute__((ext_vector_type(4))) float f32x4;
typedef __attribute__((ext_vector_type(2))) float f32x2;

__device__ __forceinline__ unsigned short f2bf(float f) {
  unsigned u = __builtin_bit_cast(unsigned, f);
  u += 0x7FFFu + ((u >> 16) & 1u);
  return (unsigned short)(u >> 16);
}
__device__ __forceinline__ float bf2f(unsigned short h) {
  unsigned u = ((unsigned)h) << 16;
  return __builtin_bit_cast(float, u);
}
__device__ __forceinline__ unsigned f32x4_to_fp8(float4 v) {
  int r = __builtin_amdgcn_cvt_pk_fp8_f32(v.x, v.y, 0, false);
  r = __builtin_amdgcn_cvt_pk_fp8_f32(v.z, v.w, r, true);
  return (unsigned)r;
}
__device__ __forceinline__ void fp8x4_to_f32(unsigned u, float* o) {
  f32x2 lo = __builtin_amdgcn_cvt_pk_f32_fp8((int)u, false);
  f32x2 hi = __builtin_amdgcn_cvt_pk_f32_fp8((int)u, true);
  o[0] = lo[0]; o[1] = lo[1]; o[2] = hi[0]; o[3] = hi[1];
}

// ---------------- CSR build (once per call) ----------------
__global__ __launch_bounds__(256) void hist_kernel(const int* __restrict__ ei,
                                                   int* __restrict__ deg, int E) {
  int e = blockIdx.x * 256 + threadIdx.x;
  if (e < E) atomicAdd(&deg[ei[E + e]], 1);
}

__global__ __launch_bounds__(256) void partial_kernel(const int* __restrict__ deg,
                                                      int* __restrict__ partial, int N) {
  __shared__ int s[256];
  int base = blockIdx.x * CHUNK;
  int sum = 0;
  for (int j = threadIdx.x; j < CHUNK; j += 256) {
    int idx = base + j;
    sum += (idx < N) ? deg[idx] : 0;
  }
  s[threadIdx.x] = sum;
  __syncthreads();
  for (int ofs = 128; ofs > 0; ofs >>= 1) {
    if (threadIdx.x < ofs) s[threadIdx.x] += s[threadIdx.x + ofs];
    __syncthreads();
  }
  if (threadIdx.x == 0) partial[blockIdx.x] = s[0];
}

__global__ __launch_bounds__(1024) void scanpart_kernel(int* partial, int nb) {
  __shared__ int s[1024];
  int tid = threadIdx.x;
  int v = (tid < nb) ? partial[tid] : 0;
  s[tid] = v;
  __syncthreads();
  for (int o = 1; o < 1024; o <<= 1) {
    int t = (tid >= o) ? s[tid - o] : 0;
    __syncthreads();
    s[tid] += t;
    __syncthreads();
  }
  if (tid < nb) partial[tid] = s[tid] - v;
}

__global__ __launch_bounds__(256) void chunkscan_kernel(const int* __restrict__ deg,
                                                        const int* __restrict__ partial,
                                                        int* __restrict__ off, int N) {
  __shared__ int ws[4];
  int base = blockIdx.x * CHUNK;
  int i0 = base + threadIdx.x * 4;
  int d[4];
  int s = 0;
#pragma unroll
  for (int k = 0; k < 4; ++k) {
    d[k] = (i0 + k < N) ? deg[i0 + k] : 0;
    s += d[k];
  }
  int lane = threadIdx.x & 63;
  int incl = s;
  for (int o = 1; o < 64; o <<= 1) {
    int v = __shfl_up(incl, o, 64);
    if (lane >= o) incl += v;
  }
  int wave = threadIdx.x >> 6;
  if (lane == 63) ws[wave] = incl;
  __syncthreads();
  int wofs = 0;
  for (int w = 0; w < wave; ++w) wofs += ws[w];
  int run = partial[blockIdx.x] + wofs + (incl - s);
#pragma unroll
  for (int k = 0; k < 4; ++k) {
    int idx = i0 + k;
    if (idx < N) {
      off[idx] = run;
      run += d[k];
      if (idx == N - 1) off[N] = run;
    }
  }
}

// scatter + fp8 convert fused: half-wave per edge, ea read is sequential
__global__ __launch_bounds__(256) void scatter_conv_kernel(
    const int* __restrict__ ei, const float* __restrict__ ea,
    const int* __restrict__ off, int* __restrict__ cursor,
    int* __restrict__ sperm, unsigned char* __restrict__ eap, int E) {
  int t = blockIdx.x * 256 + threadIdx.x;
  int lane = t & 31;
  int e = t >> 5;
  if (e >= E) return;
  int p = 0;
  if (lane == 0) {
    int dnode = ei[E + e];
    p = off[dnode] + atomicAdd(&cursor[dnode], 1);
    sperm[p] = ei[e];
  }
  p = __shfl(p, 0, 32);
  float4 v = *reinterpret_cast<const float4*>(ea + (size_t)e * D + lane * 4);
  reinterpret_cast<unsigned*>(eap)[(size_t)p * 32 + lane] = f32x4_to_fp8(v);
}

// one-time: bf16 shadow of x_in
__global__ __launch_bounds__(256) void conv_x_kernel(const float* __restrict__ x,
                                                     unsigned short* __restrict__ xbf,
                                                     long long n8) {
  long long t = (long long)blockIdx.x * 256 + threadIdx.x;
  if (t >= n8) return;
  float4 v0 = reinterpret_cast<const float4*>(x)[t * 2];
  float4 v1 = reinterpret_cast<const float4*>(x)[t * 2 + 1];
  ushort4 o0, o1;
  o0.x = f2bf(v0.x); o0.y = f2bf(v0.y); o0.z = f2bf(v0.z); o0.w = f2bf(v0.w);
  o1.x = f2bf(v1.x); o1.y = f2bf(v1.y); o1.z = f2bf(v1.z); o1.w = f2bf(v1.w);
  reinterpret_cast<ushort4*>(xbf)[t * 2] = o0;
  reinterpret_cast<ushort4*>(xbf)[t * 2 + 1] = o1;
}

// ---------------- one-time: pack weights into B-fragment order (bf16) ----------------
// per layer: [w1 | w2], each D*D shorts. slot t=(ct*4+ks)*64+l holds
// W[ks*32+((l>>4)&3)*8+i][ct*16+(l&15)], i=0..7
__global__ void pack_w_kernel(const float* __restrict__ W1, const float* __restrict__ W2,
                              unsigned short* __restrict__ pk) {
  int c = blockIdx.x;
  const float* Ws[2] = {W1 + (size_t)c * D * D, W2 + (size_t)c * D * D};
  unsigned short* base = pk + (size_t)c * 2 * D * D;
  for (int t = threadIdx.x; t < 2048; t += blockDim.x) {
    int ct = t >> 8, ks = (t >> 6) & 3, l = t & 63;
    int col = ct * 16 + (l & 15);
    int krow = ks * 32 + ((l >> 4) & 3) * 8;
    for (int w = 0; w < 2; ++w) {
      unsigned short* dst = base + (size_t)w * D * D;
      const float* W = Ws[w];
      for (int i = 0; i < 8; ++i)
        dst[(size_t)t * 8 + i] = f2bf(W[(size_t)(krow + i) * D + col]);
    }
  }
}

// ---------------- fused per-layer: dst-parallel gather (8-deep ILP) + MLP + epilogue ----------------
__global__ __launch_bounds__(256, 5) void layer_kernel(
    const float* __restrict__ x, const unsigned short* __restrict__ xbf,
    const unsigned char* __restrict__ eap,
    const int* __restrict__ off, const int* __restrict__ sperm,
    const float* __restrict__ epsp,
    const unsigned short* __restrict__ wpk,   // w1|w2 (bf16, B-frag order)
    const float* __restrict__ b1, const float* __restrict__ b2,
    const float* __restrict__ mask,
    const float* __restrict__ gamma, const float* __restrict__ beta,
    const float* __restrict__ rmean, const float* __restrict__ rvar,
    const float* __restrict__ x_in, float* __restrict__ out,
    unsigned short* __restrict__ xbf_out,
    int N, int is_last) {
  __shared__ __align__(16) unsigned short smem[BM * LDSH];  // 17408 B
  unsigned short* h_s = smem;    // h (bf16)        [phase 1..GEMM1]
  unsigned short* t_s = smem;    // T (bf16) alias  [after barrier 2]
  unsigned short* y_s = smem;    // Y (bf16) alias  [after barrier 4]

  const int tid = threadIdx.x;
  const int r0 = blockIdx.x * BM;
  const float one_eps = 1.0f + epsp[0];

  // ---- phase 1: gather-aggregate (quarter-wave per row, 8-deep batched loads) ----
  {
    const int qw = tid >> 4;        // 0..15
    const int l16 = tid & 15;       // 8 elems per lane
#pragma unroll
    for (int it = 0; it < 4; ++it) {
      int row = it * 16 + qw;
      int gr = r0 + row;
      unsigned short* ph = h_s + row * LDSH + l16 * 8;
      if (gr >= N) {
        u16x8 z = {0, 0, 0, 0, 0, 0, 0, 0};
        *reinterpret_cast<u16x8*>(ph) = z;
        continue;
      }
      int beg = off[gr], end = off[gr + 1];
      float acc[8] = {0.f, 0.f, 0.f, 0.f, 0.f, 0.f, 0.f, 0.f};
      for (int i = beg; i < end; i += 8) {
        int n = end - i;
        int idx[8], sidx[8];
#pragma unroll
        for (int k = 0; k < 8; ++k) idx[k] = (k < n) ? i + k : i;
#pragma unroll
        for (int k = 0; k < 8; ++k) sidx[k] = sperm[idx[k]];
        u16x8 xv[8];
        uint2 eu[8];
#pragma unroll
        for (int k = 0; k < 8; ++k) {
          xv[k] = *reinterpret_cast<const u16x8*>(xbf + (size_t)sidx[k] * D + l16 * 8);
          eu[k] = *reinterpret_cast<const uint2*>(eap + (size_t)idx[k] * D + l16 * 8);
        }
#pragma unroll
        for (int k = 0; k < 8; ++k) {
          if (k == 0 || k < n) {
            float ev[8];
            fp8x4_to_f32(eu[k].x, ev);
            fp8x4_to_f32(eu[k].y, ev + 4);
#pragma unroll
            for (int q = 0; q < 8; ++q)
              acc[q] += fmaxf(bf2f((unsigned short)xv[k][q]) + ev[q], 0.f);
          }
        }
      }
      const float* xd = x + (size_t)gr * D + l16 * 8;
      float4 x0 = *reinterpret_cast<const float4*>(xd);
      float4 x1 = *reinterpret_cast<const float4*>(xd + 4);
      float hv[8];
      hv[0] = fmaf(one_eps, x0.x, acc[0]); hv[1] = fmaf(one_eps, x0.y, acc[1]);
      hv[2] = fmaf(one_eps, x0.z, acc[2]); hv[3] = fmaf(one_eps, x0.w, acc[3]);
      hv[4] = fmaf(one_eps, x1.x, acc[4]); hv[5] = fmaf(one_eps, x1.y, acc[5]);
      hv[6] = fmaf(one_eps, x1.z, acc[6]); hv[7] = fmaf(one_eps, x1.w, acc[7]);
      u16x8 hi8;
#pragma unroll
      for (int q = 0; q < 8; ++q) hi8[q] = f2bf(hv[q]);
      *reinterpret_cast<u16x8*>(ph) = hi8;
    }
  }
  __syncthreads();  // barrier 1: h complete

  const int l = tid & 63;
  const int wave = tid >> 6;
  const int wm = wave >> 1;   // row half (32 rows)
  const int wn = wave & 1;    // col half (64 cols)
  const int cl = l & 15;
  const int kq = l >> 4;      // 0..3

  // ---- GEMM1: T = relu(h @ W1 + b1), pure bf16, regs-first ----
  f32x4 acc1[2][4];
  {
    s16x8 a[2][4];
#pragma unroll
    for (int rt = 0; rt < 2; ++rt) {
      int row = wm * 32 + rt * 16 + cl;
#pragma unroll
      for (int ks = 0; ks < 4; ++ks)
        a[rt][ks] = *reinterpret_cast<const s16x8*>(h_s + row * LDSH + ks * 32 + kq * 8);
    }
    const s16x8* w1 = reinterpret_cast<const s16x8*>(wpk);
#pragma unroll
    for (int ct = 0; ct < 4; ++ct) {
      int gct = wn * 4 + ct;
      f32x4 a0 = {0.f, 0.f, 0.f, 0.f};
      f32x4 a1 = {0.f, 0.f, 0.f, 0.f};
#pragma unroll
      for (int ks = 0; ks < 4; ++ks) {
        s16x8 bh = w1[(gct * 4 + ks) * 64 + l];
        a0 = __builtin_amdgcn_mfma_f32_16x16x32_bf16(a[0][ks], bh, a0, 0, 0, 0);
        a1 = __builtin_amdgcn_mfma_f32_16x16x32_bf16(a[1][ks], bh, a1, 0, 0, 0);
      }
      acc1[0][ct] = a0;
      acc1[1][ct] = a1;
    }
  }
  __syncthreads();  // barrier 2: all h reads retired -> region reusable as T

#pragma unroll
  for (int ct = 0; ct < 4; ++ct) {
    int gct = wn * 4 + ct;
    float bv = b1[gct * 16 + cl];
#pragma unroll
    for (int i = 0; i < 4; ++i) {
      t_s[(wm * 32 + kq * 4 + i) * LDSH + gct * 16 + cl] = f2bf(fmaxf(acc1[0][ct][i] + bv, 0.f));
      t_s[(wm * 32 + 16 + kq * 4 + i) * LDSH + gct * 16 + cl] = f2bf(fmaxf(acc1[1][ct][i] + bv, 0.f));
    }
  }
  __syncthreads();  // barrier 3: T complete

  // ---- GEMM2: Y = T @ W2, pure bf16, regs-first ----
  f32x4 acc2[2][4];
  {
    s16x8 a[2][4];
#pragma unroll
    for (int rt = 0; rt < 2; ++rt) {
      int row = wm * 32 + rt * 16 + cl;
#pragma unroll
      for (int ks = 0; ks < 4; ++ks)
        a[rt][ks] = *reinterpret_cast<const s16x8*>(t_s + row * LDSH + ks * 32 + kq * 8);
    }
    const s16x8* w2 = reinterpret_cast<const s16x8*>(wpk + D * D);
#pragma unroll
    for (int ct = 0; ct < 4; ++ct) {
      int gct = wn * 4 + ct;
      f32x4 a0 = {0.f, 0.f, 0.f, 0.f};
      f32x4 a1 = {0.f, 0.f, 0.f, 0.f};
#pragma unroll
      for (int ks = 0; ks < 4; ++ks) {
        s16x8 bh = w2[(gct * 4 + ks) * 64 + l];
        a0 = __builtin_amdgcn_mfma_f32_16x16x32_bf16(a[0][ks], bh, a0, 0, 0, 0);
        a1 = __builtin_amdgcn_mfma_f32_16x16x32_bf16(a[1][ks], bh, a1, 0, 0, 0);
      }
      acc2[0][ct] = a0;
      acc2[1][ct] = a1;
    }
  }
  __syncthreads();  // barrier 4: all T reads retired -> region reusable as Y

#pragma unroll
  for (int ct = 0; ct < 4; ++ct) {
    int gct = wn * 4 + ct;
#pragma unroll
    for (int i = 0; i < 4; ++i) {
      y_s[(wm * 32 + kq * 4 + i) * LDSH + gct * 16 + cl] = f2bf(acc2[0][ct][i]);
      y_s[(wm * 32 + 16 + kq * 4 + i) * LDSH + gct * 16 + cl] = f2bf(acc2[1][ct][i]);
    }
  }
  __syncthreads();  // barrier 5: Y complete

  // ---- epilogue: v = mask*(Y+b2) + x ; BN ; final relu+residual ; bf16 shadow ----
  for (int j = tid; j < BM * 16; j += 256) {
    int row = j >> 4, c8 = j & 15;
    int gr = r0 + row;
    if (gr >= N) continue;
    u16x8 yb = *reinterpret_cast<const u16x8*>(y_s + row * LDSH + c8 * 8);
    float mk = mask[gr];
    const float* xp = x + (size_t)gr * D + c8 * 8;
    float4 xv0 = *reinterpret_cast<const float4*>(xp);
    float4 xv1 = *reinterpret_cast<const float4*>(xp + 4);
    float xs[8] = {xv0.x, xv0.y, xv0.z, xv0.w, xv1.x, xv1.y, xv1.z, xv1.w};
    float vo[8];
#pragma unroll
    for (int q = 0; q < 8; ++q) {
      int col = c8 * 8 + q;
      float yv = bf2f((unsigned short)yb[q]);
      float v = fmaf(mk, yv + b2[col], xs[q]);
      v = fmaf(v - rmean[col], gamma[col] * rsqrtf(rvar[col] + 1e-5f), beta[col]);
      vo[q] = v;
    }
    if (is_last) {
      const float* xip = x_in + (size_t)gr * D + c8 * 8;
      float4 xi0 = *reinterpret_cast<const float4*>(xip);
      float4 xi1 = *reinterpret_cast<const float4*>(xip + 4);
      float xi[8] = {xi0.x, xi0.y, xi0.z, xi0.w, xi1.x, xi1.y, xi1.z, xi1.w};
#pragma unroll
      for (int q = 0; q < 8; ++q) vo[q] = xi[q] + fmaxf(vo[q], 0.f);
    } else {
      u16x8 o;
#pragma unroll
      for (int q = 0; q < 8; ++q) o[q] = f2bf(vo[q]);
      *reinterpret_cast<u16x8*>(xbf_out + (size_t)gr * D + c8 * 8) = o;
    }
    float4 w0 = make_float4(vo[0], vo[1], vo[2], vo[3]);
    float4 w1 = make_float4(vo[4], vo[5], vo[6], vo[7]);
    float* op = out + (size_t)gr * D + c8 * 8;
    *reinterpret_cast<float4*>(op) = w0;
    *reinterpret_cast<float4*>(op + 4) = w1;
  }
}

static inline char* align_up(char* p, size_t a) {
  return (char*)(((size_t)p + a - 1) & ~(a - 1));
}

extern "C" void kernel_launch(void* const* d_in, const int* in_sizes, int n_in,
                              void* d_out, int out_size, void* d_ws, size_t ws_size,
                              hipStream_t stream) {
  const float* x_in  = (const float*)d_in[0];
  const int*   ei    = (const int*)d_in[1];
  const float* ea    = (const float*)d_in[2];
  const float* masks = (const float*)d_in[3];
  const float* W1    = (const float*)d_in[4];
  const float* b1    = (const float*)d_in[5];
  const float* W2    = (const float*)d_in[6];
  const float* b2    = (const float*)d_in[7];
  const float* eps   = (const float*)d_in[8];
  const float* gamma = (const float*)d_in[9];
  const float* beta  = (const float*)d_in[10];
  const float* rmean = (const float*)d_in[11];
  const float* rvar  = (const float*)d_in[12];
  const int N = in_sizes[0] / D;
  const int E = in_sizes[1] / 2;
  const int C = in_sizes[8];
  const int nb = (N + CHUNK - 1) / CHUNK;

  // workspace layout
  char* w = (char*)d_ws;
  float* xalt  = (float*)w;  w += (size_t)N * D * sizeof(float);
  int* deg     = (int*)w;    w += (size_t)N * sizeof(int);
  int* off     = (int*)w;    w += (size_t)(N + 1) * sizeof(int);
  int* cursor  = (int*)w;    w += (size_t)N * sizeof(int);
  int* partial = (int*)w;    w += (size_t)(nb + 1) * sizeof(int);
  int* sperm   = (int*)w;    w += (size_t)E * sizeof(int);
  w = align_up(w, 128);
  unsigned short* xbfA = (unsigned short*)w;  w += (size_t)N * D * sizeof(unsigned short);
  unsigned short* xbfB = (unsigned short*)w;  w += (size_t)N * D * sizeof(unsigned short);
  unsigned short* wpk  = (unsigned short*)w;  w += (size_t)C * 2 * D * D * sizeof(unsigned short);
  w = align_up(w, 128);
  unsigned char* eap = (unsigned char*)w;     // E * 128 bytes (fp8 e4m3)

  // ---- one-time: CSR + permuted fp8 edge_attr + packed weights + bf16 x_in ----
  hipMemsetAsync(deg, 0, (size_t)N * sizeof(int), stream);
  hipMemsetAsync(cursor, 0, (size_t)N * sizeof(int), stream);
  hist_kernel<<<(E + 255) / 256, 256, 0, stream>>>(ei, deg, E);
  partial_kernel<<<nb, 256, 0, stream>>>(deg, partial, N);
  scanpart_kernel<<<1, 1024, 0, stream>>>(partial, nb);
  chunkscan_kernel<<<nb, 256, 0, stream>>>(deg, partial, off, N);
  scatter_conv_kernel<<<(E + 7) / 8, 256, 0, stream>>>(ei, ea, off, cursor, sperm, eap, E);
  pack_w_kernel<<<C, 256, 0, stream>>>(W1, W2, wpk);
  long long n8 = (long long)N * D / 8;
  conv_x_kernel<<<(int)((n8 + 255) / 256), 256, 0, stream>>>(x_in, xbfA, n8);

  const int blocks = (N + BM - 1) / BM;
  const float* xc = x_in;
  const unsigned short* xbf_cur = xbfA;
  for (int c = 0; c < C; ++c) {
    float* dst = (((C - 1 - c) & 1) == 0) ? (float*)d_out : xalt;
    unsigned short* xbf_next = (xbf_cur == xbfA) ? xbfB : xbfA;
    layer_kernel<<<blocks, 256, 0, stream>>>(
        xc, xbf_cur, eap, off, sperm, eps + c,
        wpk + (size_t)c * 2 * D * D,
        b1 + (size_t)c * D, b2 + (size_t)c * D,
        masks + (size_t)c * N,
        gamma + (size_t)c * D, beta + (size_t)c * D,
        rmean + (size_t)c * D, rvar + (size_t)c * D,
        x_in, dst, xbf_next, N, (c == C - 1) ? 1 : 0);
    xc = dst;
    xbf_cur = xbf_next;
  }
}